// Round 3
// baseline (118.843 us; speedup 1.0000x reference)
//
#include <hip/hip_runtime.h>

// Vanilla RNN B=4096 S=512 I=1 H=16 O=1 — persistent-RNN on the matrix core.
//
// One wave owns 16 batch columns. Each step:
//   Y(16x16) = A(=-2*S2LE*W_hh, f16, loaded once) x B(=g, f16) + C(=xp, f32)
// via one v_mfma_f32_16x16x16_f16. Layout identity (guide §3, m89/m120):
//   D: [m=quad*4+reg][n=lane&15]   ==   B: [k=quad*4+i][n=lane&15]
// so the elementwise tanh (g-form: g = rcp(exp2(y)+1), h = 1-2g) feeds the
// next step's B-fragment with ZERO cross-lane ops. This replaces R2's
// 15 DPP rotations + 16 serial fmas per step with 1 MFMA.
//
// g-trick: h = 1-2g  =>  W_hh.h = rowsum(W_hh) - 2*W_hh.g ; rowsum folds
// into the bias, -2*S2LE into A. exp2-based sigmoid: S2LE = 2*log2(e).

#define S2LE 2.8853900817779268f

typedef _Float16 half4 __attribute__((ext_vector_type(4)));
typedef float float4_ __attribute__((ext_vector_type(4)));

__global__ __launch_bounds__(64) void rnn_kernel(
    const float* __restrict__ x,
    const float* __restrict__ W_ih,
    const float* __restrict__ W_hh,
    const float* __restrict__ b_ih,
    const float* __restrict__ b_hh,
    const float* __restrict__ W_fc,
    const float* __restrict__ b_fc,
    float* __restrict__ out)
{
    const int l  = (int)threadIdx.x;   // 0..63
    const int n  = l & 15;             // batch column within the group
    const int q  = l >> 4;             // quad
    const int bb = (int)blockIdx.x * 16;

    // A-fragment: A[m][k], m = lane&15, k = 4*quad + i  (i = reg index).
    half4 afrag;
#pragma unroll
    for (int i = 0; i < 4; ++i)
        afrag[i] = (_Float16)(-2.0f * S2LE * W_hh[n * 16 + (4 * q + i)]);

    // Per-reg row constants for rows i = 4*quad + r (the rows this lane's
    // C/D registers correspond to).
    float wih[4], bias[4], wfc[4];
#pragma unroll
    for (int r = 0; r < 4; ++r) {
        int i = 4 * q + r;
        float sw = 0.0f;
#pragma unroll
        for (int j = 0; j < 16; ++j) sw += W_hh[i * 16 + j];
        wih[r]  = W_ih[i] * S2LE;
        bias[r] = (b_ih[i] + b_hh[i] + sw) * S2LE;
        wfc[r]  = W_fc[i];
    }

    // x for this lane's batch column (all 4 quads read the same row; L1
    // broadcasts). float4 chunk = 4 timesteps; 2-chunk-ahead prefetch.
    const float4_* __restrict__ xv =
        (const float4_*)(x + (size_t)(bb + n) * 512);

    half4 bfrag;
    bfrag[0] = bfrag[1] = bfrag[2] = bfrag[3] = (_Float16)0.5f;  // h = 0
    float4_ gs;  // last step's g in f32 (for the exact epilogue)

    float4_ xc = xv[0];
    float4_ xn = xv[1];

#define STEP(XT) do { \
    float4_ cc; \
    cc[0] = fmaf((XT), wih[0], bias[0]); \
    cc[1] = fmaf((XT), wih[1], bias[1]); \
    cc[2] = fmaf((XT), wih[2], bias[2]); \
    cc[3] = fmaf((XT), wih[3], bias[3]); \
    float4_ y = __builtin_amdgcn_mfma_f32_16x16x16f16(afrag, bfrag, cc, 0, 0, 0); \
    gs[0] = __builtin_amdgcn_rcpf(__builtin_amdgcn_exp2f(y[0]) + 1.0f); \
    gs[1] = __builtin_amdgcn_rcpf(__builtin_amdgcn_exp2f(y[1]) + 1.0f); \
    gs[2] = __builtin_amdgcn_rcpf(__builtin_amdgcn_exp2f(y[2]) + 1.0f); \
    gs[3] = __builtin_amdgcn_rcpf(__builtin_amdgcn_exp2f(y[3]) + 1.0f); \
    bfrag[0] = (_Float16)gs[0]; \
    bfrag[1] = (_Float16)gs[1]; \
    bfrag[2] = (_Float16)gs[2]; \
    bfrag[3] = (_Float16)gs[3]; \
} while (0)

#pragma unroll 1
    for (int c = 0; c < 128; ++c) {
        float4_ xf = xv[(c + 2) & 127];  // prefetch (wraps harmlessly)
        STEP(xc[0]);
        STEP(xc[1]);
        STEP(xc[2]);
        STEP(xc[3]);
        xc = xn;
        xn = xf;
    }
#undef STEP

    // out[b] = sum_i wfc[i]*h[i] + bfc,  h = 1 - 2g (use exact f32 g).
    float p = 0.0f;
#pragma unroll
    for (int r = 0; r < 4; ++r)
        p = fmaf(wfc[r], fmaf(-2.0f, gs[r], 1.0f), p);
    // Reduce across the 4 quads (lanes n, n+16, n+32, n+48).
    p += __shfl_xor(p, 16, 64);
    p += __shfl_xor(p, 32, 64);
    if (q == 0) out[bb + n] = p + b_fc[0];
}

extern "C" void kernel_launch(void* const* d_in, const int* in_sizes, int n_in,
                              void* d_out, int out_size, void* d_ws, size_t ws_size,
                              hipStream_t stream) {
    const float* x    = (const float*)d_in[0];
    const float* W_ih = (const float*)d_in[1];
    const float* W_hh = (const float*)d_in[2];
    const float* b_ih = (const float*)d_in[3];
    const float* b_hh = (const float*)d_in[4];
    const float* W_fc = (const float*)d_in[5];
    const float* b_fc = (const float*)d_in[6];
    float* out = (float*)d_out;

    rnn_kernel<<<256, 64, 0, stream>>>(x, W_ih, W_hh, b_ih, b_hh, W_fc, b_fc, out);
}

// Round 5
// 104.679 us; speedup vs baseline: 1.1353x; 1.1353x over previous
//
#include <hip/hip_runtime.h>

// Vanilla RNN B=4096 S=512 I=1 H=16 O=1 — latency-optimized serial chain.
// Lane = (batch, h-row); 16 lanes/batch; 1024 waves = 1 wave/SIMD (hard
// parallelism cap). Wall time = 512 * per-step critical-path latency, so
// everything targets chain latency + solo-wave issue count.
//
// R4 vs R2 (235 cyc/step): matvec via v_dot2_f32_f16 on packed f16 pairs.
//   pk0 = cvt_pkrtz(g, ror1(g))            -> (g_i, g_{rho1(i)})
//   ror:N of pk0 gives (g_{rhoN(i)}, g_{rho(N+1)(i)})  [rotations compose]
//   8 fdot2 (f32 accumulate) replace 16 fmas; 7 packed rotations replace 15.
// Weights self-calibrated against the HW's actual rotation permutation.
// g-trick: state g = 1/(2^y+1), h = 1-2g; rowsum(W_hh) folded into bias,
// -2*S2LE into weights. Only g and W_hh are f16 (R3 measured ~1e-3 absmax
// for this quantization; threshold 5.6e-3). Accumulation stays f32.
//
// R4b: type fix only — cvt_pkrtz/fdot2 use __fp16 ext vectors, not _Float16.

#define S2LE 2.8853900817779268f  // 2*log2(e)

typedef __fp16 half2_ __attribute__((ext_vector_type(2)));
typedef float float4_ __attribute__((ext_vector_type(4)));

#define ROTI(v, N) __builtin_amdgcn_mov_dpp((v), 0x120 + (N), 0xF, 0xF, 0)
#define ROTF(v, N) __int_as_float(__builtin_amdgcn_mov_dpp(__float_as_int(v), 0x120 + (N), 0xF, 0xF, 0))
#define ROTP(v, N) __builtin_bit_cast(half2_, __builtin_amdgcn_mov_dpp(__builtin_bit_cast(int, (v)), 0x120 + (N), 0xF, 0xF, 0))

__global__ __launch_bounds__(64) void rnn_kernel(
    const float* __restrict__ x,
    const float* __restrict__ W_ih,
    const float* __restrict__ W_hh,
    const float* __restrict__ b_ih,
    const float* __restrict__ b_hh,
    const float* __restrict__ W_fc,
    const float* __restrict__ b_fc,
    float* __restrict__ out)
{
    const int li = (int)(threadIdx.x & 15u);
    const int b  = (int)((blockIdx.x * 64u + threadIdx.x) >> 4);

    const float* __restrict__ row = W_hh + li * 16;

    float sw = 0.0f;
#pragma unroll
    for (int j = 0; j < 16; ++j) sw += row[j];

    const float wsc = -2.0f * S2LE;

    // Packed self-calibrated weights: w2[k] pairs offsets (2k, 2k+1).
    // slot0 = W[i][rho_{2k}(i)], slot1 = W[i][rho_1(rho_{2k}(i))].
    half2_ w2[8];
    {
        const int r1i = ROTI(li, 1);
        w2[0][0] = (__fp16)(wsc * row[li]);
        w2[0][1] = (__fp16)(wsc * row[r1i]);
#define LW(K, N) { int s0_ = ROTI(li, N); int s1_ = ROTI(r1i, N); \
        w2[K][0] = (__fp16)(wsc * row[s0_]); \
        w2[K][1] = (__fp16)(wsc * row[s1_]); }
        LW(1, 2) LW(2, 4) LW(3, 6) LW(4, 8) LW(5, 10) LW(6, 12) LW(7, 14)
#undef LW
    }

    const float wih  = W_ih[li] * S2LE;
    const float bias = (b_ih[li] + b_hh[li] + sw) * S2LE;
    const float wfc  = W_fc[li];
    const float bfc  = b_fc[0];

    const float4_* __restrict__ xv = (const float4_*)(x + (size_t)b * 512);

    float g = 0.5f;          // represents h = 0
    float4_ xc = xv[0];
    float4_ xn = xv[1];

    // One step: pack -> 7 packed rotations -> 8 fdot2 (4 chains of 2) ->
    // tree add -> exp2 -> add -> rcp.
#define STEP(XP) do { \
    float r1_ = ROTF(g, 1); \
    half2_ pk0 = __builtin_amdgcn_cvt_pkrtz(g, r1_); \
    half2_ p2_  = ROTP(pk0, 2); \
    half2_ p4_  = ROTP(pk0, 4); \
    half2_ p6_  = ROTP(pk0, 6); \
    half2_ p8_  = ROTP(pk0, 8); \
    half2_ p10_ = ROTP(pk0, 10); \
    half2_ p12_ = ROTP(pk0, 12); \
    half2_ p14_ = ROTP(pk0, 14); \
    float c0_ = __builtin_amdgcn_fdot2(pk0,  w2[0], (XP), false); \
    c0_ = __builtin_amdgcn_fdot2(p2_,  w2[1], c0_, false); \
    float c1_ = __builtin_amdgcn_fdot2(p4_,  w2[2], 0.0f, false); \
    c1_ = __builtin_amdgcn_fdot2(p6_,  w2[3], c1_, false); \
    float c2_ = __builtin_amdgcn_fdot2(p8_,  w2[4], 0.0f, false); \
    c2_ = __builtin_amdgcn_fdot2(p10_, w2[5], c2_, false); \
    float c3_ = __builtin_amdgcn_fdot2(p12_, w2[6], 0.0f, false); \
    c3_ = __builtin_amdgcn_fdot2(p14_, w2[7], c3_, false); \
    float s_ = (c0_ + c1_) + (c2_ + c3_); \
    float e_ = __builtin_amdgcn_exp2f(s_); \
    g = __builtin_amdgcn_rcpf(e_ + 1.0f); \
} while (0)

#pragma unroll 1
    for (int c = 0; c < 128; ++c) {
        float4_ xf = xv[(c + 2) & 127];  // prefetch (wraps harmlessly)
        // x-projections depend only on x: issue in the trans-latency shadow.
        float xp0 = fmaf(xc[0], wih, bias);
        float xp1 = fmaf(xc[1], wih, bias);
        float xp2 = fmaf(xc[2], wih, bias);
        float xp3 = fmaf(xc[3], wih, bias);
        STEP(xp0);
        STEP(xp1);
        STEP(xp2);
        STEP(xp3);
        xc = xn;
        xn = xf;
    }
#undef STEP

    // out[b] = sum_i wfc_i * h_i + bfc, h = 1 - 2g (exact f32 g).
    float p = fmaf(-2.0f * wfc, g, wfc);
    p += ROTF(p, 8);
    p += ROTF(p, 4);
    p += ROTF(p, 2);
    p += ROTF(p, 1);
    if (li == 0) out[b] = p + bfc;
}

extern "C" void kernel_launch(void* const* d_in, const int* in_sizes, int n_in,
                              void* d_out, int out_size, void* d_ws, size_t ws_size,
                              hipStream_t stream) {
    const float* x    = (const float*)d_in[0];
    const float* W_ih = (const float*)d_in[1];
    const float* W_hh = (const float*)d_in[2];
    const float* b_ih = (const float*)d_in[3];
    const float* b_hh = (const float*)d_in[4];
    const float* W_fc = (const float*)d_in[5];
    const float* b_fc = (const float*)d_in[6];
    float* out = (float*)d_out;

    rnn_kernel<<<1024, 64, 0, stream>>>(x, W_ih, W_hh, b_ih, b_hh, W_fc, b_fc, out);
}